// Round 21
// baseline (1097.838 us; speedup 1.0000x reference)
//
#include <hip/hip_runtime.h>

#define DD      32
#define TE_DIM  64
#define NHID    128
#define XA_DIM  71   // 2 (src) + 2 (dst) + 3 (feat) + 64 (te)
#define MSG_DIM 69   // 2 (src) + 3 (feat) + 64 (te)
#define SCAN_BLK 1024
#define INV2PI  0.15915494309189535f
#define TWO_LOG2E 2.885390081777927f   // 2*log2(e)

typedef __attribute__((ext_vector_type(8))) short bf16x8;
typedef __attribute__((ext_vector_type(4))) float f32x4;
typedef __attribute__((ext_vector_type(2))) float f32x2;
typedef __attribute__((ext_vector_type(4))) unsigned int u32x4;

__device__ __forceinline__ float fast_tanh(float x) {
    return 1.0f - 2.0f / (__builtin_amdgcn_exp2f(x * TWO_LOG2E) + 1.0f);
}

__device__ __forceinline__ unsigned short f32_to_bf16(float x) {
    unsigned u = __float_as_uint(x);
    unsigned r = (u + 0x7FFF + ((u >> 16) & 1)) >> 16;   // RNE, finite inputs
    return (unsigned short)r;
}
__device__ __forceinline__ float bf16_to_f32(unsigned short h) {
    return __uint_as_float(((unsigned)h) << 16);
}

// RNE-hi split pack: hi = rne_bf16(v), lo = trunc_bf16(v - hi). lo absorbs the
// rounding residual exactly -> 3-product MFMA accuracy ~f32.
__device__ __forceinline__ void pack_split_rne(const float* av, bf16x8& hi, bf16x8& lo) {
    union { u32x4 u; bf16x8 b; } H, L;
#pragma unroll
    for (int p = 0; p < 4; p++) {
        unsigned ua = __float_as_uint(av[2 * p]);
        unsigned ub = __float_as_uint(av[2 * p + 1]);
        unsigned ra = ua + 0x7FFF + ((ua >> 16) & 1);
        unsigned rb = ub + 0x7FFF + ((ub >> 16) & 1);
        H.u[p] = __builtin_amdgcn_perm(rb, ra, 0x07060302);
        float la = av[2 * p]     - __uint_as_float(ra & 0xFFFF0000u);
        float lb = av[2 * p + 1] - __uint_as_float(rb & 0xFFFF0000u);
        L.u[p] = __builtin_amdgcn_perm(__float_as_uint(lb), __float_as_uint(la), 0x07060302);
    }
    hi = H.b;
    lo = L.b;
}

// ---------------- CSR build ----------------

__global__ void k_hist(const int* __restrict__ dst, int* __restrict__ counts, int E) {
    int e = blockIdx.x * blockDim.x + threadIdx.x;
    if (e < E) atomicAdd(&counts[dst[e]], 1);
}

__global__ void __launch_bounds__(256) k_scan1(
    const int* __restrict__ counts, int* __restrict__ offs,
    int* __restrict__ bsums, int n)
{
    __shared__ int lds[256];
    int t = threadIdx.x;
    int base = blockIdx.x * SCAN_BLK + t * 4;
    int v[4]; int tsum = 0;
#pragma unroll
    for (int i = 0; i < 4; i++) { v[i] = (base + i < n) ? counts[base + i] : 0; tsum += v[i]; }
    lds[t] = tsum;
    __syncthreads();
    for (int off = 1; off < 256; off <<= 1) {
        int x = (t >= off) ? lds[t - off] : 0;
        __syncthreads();
        lds[t] += x;
        __syncthreads();
    }
    int excl = lds[t] - tsum;
    if (t == 255) bsums[blockIdx.x] = lds[255];
    int run = excl;
#pragma unroll
    for (int i = 0; i < 4; i++) {
        if (base + i < n) offs[base + i] = run;
        run += v[i];
    }
}

// single-block parallel exclusive scan of nb (<=128) block sums
__global__ void __launch_bounds__(128) k_scan2p(int* bsums, int nb) {
    __shared__ int lds[128];
    int t = threadIdx.x;
    int v = (t < nb) ? bsums[t] : 0;
    lds[t] = v;
    __syncthreads();
    for (int off = 1; off < 128; off <<= 1) {
        int x = (t >= off) ? lds[t - off] : 0;
        __syncthreads();
        lds[t] += x;
        __syncthreads();
    }
    if (t < nb) bsums[t] = lds[t] - v;
}

__global__ void k_scan3(int* __restrict__ offs, int* __restrict__ woff,
                        const int* __restrict__ bsums, int n, int E)
{
    int i = blockIdx.x * blockDim.x + threadIdx.x;
    if (i < n) {
        int v = offs[i] + bsums[i >> 10];
        offs[i] = v;
        woff[i] = v;
        if (i == 0) offs[n] = E;
    }
}

__global__ void k_fill(const int* __restrict__ dst, int* __restrict__ woff,
                       int* __restrict__ edge_ids, int* __restrict__ perm, int E)
{
    int e = blockIdx.x * blockDim.x + threadIdx.x;
    if (e < E) {
        int pos = atomicAdd(&woff[dst[e]], 1);
        edge_ids[pos] = e;
        perm[e] = pos;
    }
}

// ---------------- weight pre-pack into MFMA B-fragment layout ----------------

__global__ void k_prep(const float* __restrict__ w1, const float* __restrict__ w2,
                       const float* __restrict__ w3, const float* __restrict__ watt,
                       short* __restrict__ pk1, short* __restrict__ pk2,
                       short* __restrict__ pk3, short* __restrict__ pkatt)
{
    int idx = blockIdx.x * blockDim.x + threadIdx.x;
    const float* w; short* pk; int S, K, li;
    if (idx < 12288)              { w = w1;   pk = pk1;   S = 3; K = 69;  li = idx; }
    else if (idx < 28672)         { w = w2;   pk = pk2;   S = 4; K = 128; li = idx - 12288; }
    else if (idx < 45056)         { w = w3;   pk = pk3;   S = 4; K = 128; li = idx - 28672; }
    else if (idx < 57344)         { w = watt; pk = pkatt; S = 3; K = 71;  li = idx - 45056; }
    else return;
    int i    = li & 7;
    int lane = (li >> 3) & 63;
    int ts   = li >> 9;            // t*S + s
    int s = ts % S, t = ts / S;
    int col = 16 * t + (lane & 15);
    int k   = 32 * s + (lane >> 4) * 8 + i;
    float v = (k < K) ? w[col * K + k] : 0.0f;
    unsigned short hi = f32_to_bf16(v);
    float lo = v - bf16_to_f32(hi);
    int plane = 8 * S * 512;
    pk[li]         = (short)hi;
    pk[li + plane] = (short)f32_to_bf16(lo);
}

// ---------------- MFMA attention logits ----------------
// 64 edges/block, 4 waves; wave w owns rows [16w,16w+16), 1 A-row per thread.
// Native v_sin/v_cos trig, RNE split-pack fragments, global B reads (R19
// LDS staging measured neutral). Epilogue att routed through a 64-float LDS
// buffer (not shfls) to keep VGPR <= 64; __launch_bounds__(256,8) pins the
// allocator to the 8-wave/SIMD occupancy bracket (m69: brackets at 64/128/256).
// store_streams: one 32B record per edge at CSR slot perm[e].

__global__ void __launch_bounds__(256, 8) k_att_mfma(
    const float* __restrict__ X_msg, const float* __restrict__ feature,
    const float* __restrict__ te_w, const float* __restrict__ te_lam,
    const float* __restrict__ shared_w, const float* __restrict__ shared_b,
    const short* __restrict__ pk_att, const float* __restrict__ w_att_b,
    const float* __restrict__ va,
    const int* __restrict__ src, const int* __restrict__ dst,
    const int* __restrict__ dst_lane,
    const int* __restrict__ perm, float* __restrict__ att_perm,
    float* __restrict__ rec8, int store_streams, int E)
{
    __shared__ float rowv[7][64];    // xs0,xs1,xd0,xd1,f0,dt,f2 (SoA)
    __shared__ float attS[64];
    __shared__ int   lns[64];
    __shared__ float lam8[8];
    __shared__ float twr[8][33];     // te_w * INV2PI, padded
    __shared__ float swr[32], sbr[32];

    int tid = threadIdx.x;
    int wave = tid >> 6, lane = tid & 63;
    int block0 = blockIdx.x * 64;

    twr[tid >> 5][tid & 31] = te_w[tid] * INV2PI;       // 256 = 8*32
    if (tid < 32) { swr[tid] = shared_w[tid] * INV2PI; sbr[tid] = shared_b[tid] * INV2PI; }
    if (tid < 8)  { float rl = te_lam[tid]; lam8[tid] = __expf(-rl * rl); }
    if (tid < 64) {
        int e = block0 + tid;
        if (e < E) {
            int s = src[e], d = dst[e];
            f32x4 f4 = *(const f32x4*)&feature[e * 4];
            f32x2 xs = *(const f32x2*)&X_msg[s * 2];
            f32x2 xd = *(const f32x2*)&X_msg[d * 2];
            rowv[0][tid] = xs[0]; rowv[1][tid] = xs[1];
            rowv[2][tid] = xd[0]; rowv[3][tid] = xd[1];
            rowv[4][tid] = f4[0]; rowv[5][tid] = f4[1]; rowv[6][tid] = f4[2];
            lns[tid] = dst_lane[e];
        } else {
#pragma unroll
            for (int c = 0; c < 7; c++) rowv[c][tid] = 0.0f;
            lns[tid] = 0;
        }
    }
    __syncthreads();

    const int R = wave * 16;
    const int rlo = lane & 15;
    const int r0 = R + rlo;
    const int g = lane >> 4;
    const int kbase = g * 8;
    int e_row = block0 + r0;

    float dt = rowv[5][r0];
    int ln = lns[r0];
    float lam = lam8[ln], oml = 1.0f - lam;

    float tes[8], tec[8];
#pragma unroll
    for (int i = 0; i < 8; i++) {
        int k = (kbase + i + 25) & 31;
        float rev1 = dt * twr[ln][k];
        float rev2 = fmaf(dt, swr[k], sbr[k]);
        float s1 = __builtin_amdgcn_sinf(rev1), c1 = __builtin_amdgcn_cosf(rev1);
        float s2 = __builtin_amdgcn_sinf(rev2), c2 = __builtin_amdgcn_cosf(rev2);
        tes[i] = oml * s1 + lam * s2;
        tec[i] = oml * c1 + lam * c2;
    }

    f32x4 acc[8];
#pragma unroll
    for (int t = 0; t < 8; t++) acc[t] = (f32x4){0.f, 0.f, 0.f, 0.f};

#pragma unroll
    for (int s = 0; s < 3; s++) {
        float av[8];
#pragma unroll
        for (int i = 0; i < 8; i++) {
            int c = 32 * s + kbase + i;
            if (s == 0)      av[i] = (c < 7)  ? rowv[c][r0] : tes[i];
            else if (s == 1) av[i] = (c < 39) ? tes[i] : tec[i];
            else             av[i] = (c < 71) ? tec[i] : 0.0f;
        }
        bf16x8 ah, al;
        pack_split_rne(av, ah, al);
#pragma unroll
        for (int t = 0; t < 8; t++) {
            const short* bp = pk_att + ((t * 3 + s) * 64 + lane) * 8;
            bf16x8 bh = *(const bf16x8*)bp;
            bf16x8 bl = *(const bf16x8*)(bp + 12288);
            acc[t] = __builtin_amdgcn_mfma_f32_16x16x32_bf16(ah, bh, acc[t], 0, 0, 0);
            acc[t] = __builtin_amdgcn_mfma_f32_16x16x32_bf16(ah, bl, acc[t], 0, 0, 0);
            acc[t] = __builtin_amdgcn_mfma_f32_16x16x32_bf16(al, bh, acc[t], 0, 0, 0);
        }
    }

    // epilogue: att_row = sum_j va[j] * tanh(pre[j] + b[j])
    int ccol = lane & 15;
    float sums[4] = {0.f, 0.f, 0.f, 0.f};
#pragma unroll
    for (int t = 0; t < 8; t++) {
        float b = w_att_b[16 * t + ccol];
        float v = va[16 * t + ccol];
#pragma unroll
        for (int r = 0; r < 4; r++)
            sums[r] += v * fast_tanh(acc[t][r] + b);
    }
#pragma unroll
    for (int mask = 1; mask < 16; mask <<= 1)
#pragma unroll
        for (int r = 0; r < 4; r++)
            sums[r] += __shfl_xor(sums[r], mask);
    // sums[r] uniform across each 16-lane group; group g holds edges R+4g+r.

    if (store_streams) {
        int q = lane & 15;
        if (q < 4) attS[R + 4 * g + q] = sums[q];
        __syncthreads();
        if (g == 0 && e_row < E) {
            int pe = perm[e_row];
            f32x4 rc0 = {rowv[0][r0], rowv[1][r0], rowv[4][r0], rowv[6][r0]};
            f32x4 rc1 = {dt, __int_as_float(ln), attS[r0], 0.0f};
            *(f32x4*)&rec8[(size_t)pe * 8]     = rc0;
            *(f32x4*)&rec8[(size_t)pe * 8 + 4] = rc1;
        }
    } else {
        int q = lane & 15;
        if (q < 4) {
            int e2 = block0 + R + 4 * g + q;
            if (e2 < E) att_perm[perm[e2]] = sums[q];
        }
    }
}

// ---------------- streaming wave-split gather (32B records, slot order) -----

__global__ void __launch_bounds__(256) k_gather_stream(
    const float* __restrict__ te_w, const float* __restrict__ te_lam,
    const float* __restrict__ shared_w, const float* __restrict__ shared_b,
    const float* __restrict__ rec8,
    const int* __restrict__ offs, float* __restrict__ h_att, int n)
{
    __shared__ float twr[8][33];
    __shared__ float swr[32], sbr[32];
    __shared__ float lam8[8];
    int tid = threadIdx.x;
    twr[tid >> 5][tid & 31] = te_w[tid] * INV2PI;
    if (tid < 32) { swr[tid] = shared_w[tid] * INV2PI; sbr[tid] = shared_b[tid] * INV2PI; }
    if (tid < 8)  { float rl = te_lam[tid]; lam8[tid] = __expf(-rl * rl); }
    __syncthreads();

    int node = blockIdx.x * 16 + (tid >> 4);
    int l = tid & 15;
    if (node >= n) return;
    int beg = offs[node], end = offs[node + 1];

    float mx = -INFINITY;
    for (int slot = beg + l; slot < end; slot += 16)
        mx = fmaxf(mx, rec8[(size_t)slot * 8 + 6]);
#pragma unroll
    for (int m = 1; m < 16; m <<= 1)
        mx = fmaxf(mx, __shfl_xor(mx, m, 16));

    const int k0 = 2 * l, k1 = k0 + 1;
    const float sw0 = swr[k0], sb0 = sbr[k0];
    const float sw1 = swr[k1], sb1 = sbr[k1];

    float a_s0 = 0.f, a_s1 = 0.f, a_c0 = 0.f, a_c1 = 0.f, a_lead = 0.f, denom = 0.f;
    for (int slot = beg; slot < end; slot++) {
        f32x4 rc1 = *(const f32x4*)&rec8[(size_t)slot * 8 + 4];
        float dt = rc1[0];
        int ln = __float_as_int(rc1[1]);
        float ex = __expf(rc1[2] - mx);
        denom += ex;
        float lam = lam8[ln], oml = 1.0f - lam;
        float r10 = dt * twr[ln][k0];
        float r11 = dt * twr[ln][k1];
        float r20 = fmaf(dt, sw0, sb0);
        float r21 = fmaf(dt, sw1, sb1);
        a_s0 += ex * (oml * __builtin_amdgcn_sinf(r10) + lam * __builtin_amdgcn_sinf(r20));
        a_s1 += ex * (oml * __builtin_amdgcn_sinf(r11) + lam * __builtin_amdgcn_sinf(r21));
        a_c0 += ex * (oml * __builtin_amdgcn_cosf(r10) + lam * __builtin_amdgcn_cosf(r20));
        a_c1 += ex * (oml * __builtin_amdgcn_cosf(r11) + lam * __builtin_amdgcn_cosf(r21));
        if (l < 5) {
            f32x4 rc0 = *(const f32x4*)&rec8[(size_t)slot * 8];
            float lead = (l == 0) ? rc0[0] : (l == 1) ? rc0[1]
                       : (l == 2) ? rc0[2] : (l == 3) ? dt : rc0[3];
            a_lead += ex * lead;
        }
    }
    float inv = (denom > 0.0f) ? 1.0f / denom : 0.0f;
    float* row = h_att + (size_t)node * MSG_DIM;
    if (l < 5) row[l] = a_lead * inv;
    row[5 + k0]      = a_s0 * inv;
    row[5 + k1]      = a_s1 * inv;
    row[5 + DD + k0] = a_c0 * inv;
    row[5 + DD + k1] = a_c1 * inv;
}

// ---------------- fallback gather (used if ws too small) -------

__global__ void __launch_bounds__(256) k_gather_wave(
    const float* __restrict__ X_msg, const float* __restrict__ feature,
    const float* __restrict__ te_w, const float* __restrict__ te_lam,
    const float* __restrict__ shared_w, const float* __restrict__ shared_b,
    const int* __restrict__ src, const int* __restrict__ dst_lane,
    const float* __restrict__ att_perm,
    const int* __restrict__ offs, const int* __restrict__ edge_ids,
    float* __restrict__ h_att, int n)
{
    __shared__ float twr[8][33];
    __shared__ float swr[32], sbr[32];
    __shared__ float lam8[8];
    int tid = threadIdx.x;
    twr[tid >> 5][tid & 31] = te_w[tid] * INV2PI;
    if (tid < 32) { swr[tid] = shared_w[tid] * INV2PI; sbr[tid] = shared_b[tid] * INV2PI; }
    if (tid < 8)  { float rl = te_lam[tid]; lam8[tid] = __expf(-rl * rl); }
    __syncthreads();

    int node = blockIdx.x * 16 + (tid >> 4);
    int l = tid & 15;
    if (node >= n) return;
    int beg = offs[node], end = offs[node + 1];

    float mx = -INFINITY;
    for (int slot = beg + l; slot < end; slot += 16)
        mx = fmaxf(mx, att_perm[slot]);
#pragma unroll
    for (int m = 1; m < 16; m <<= 1)
        mx = fmaxf(mx, __shfl_xor(mx, m, 16));

    const int k0 = 2 * l, k1 = k0 + 1;
    const float sw0 = swr[k0], sb0 = sbr[k0];
    const float sw1 = swr[k1], sb1 = sbr[k1];

    float a_s0 = 0.f, a_s1 = 0.f, a_c0 = 0.f, a_c1 = 0.f, a_lead = 0.f, denom = 0.f;
    for (int slot = beg; slot < end; slot++) {
        int e = edge_ids[slot];
        float ex = __expf(att_perm[slot] - mx);
        denom += ex;
        int ln = dst_lane[e];
        f32x4 f4 = *(const f32x4*)&feature[e * 4];
        float dt = f4[1];
        float lam = lam8[ln], oml = 1.0f - lam;
        float r10 = dt * twr[ln][k0];
        float r11 = dt * twr[ln][k1];
        float r20 = fmaf(dt, sw0, sb0);
        float r21 = fmaf(dt, sw1, sb1);
        a_s0 += ex * (oml * __builtin_amdgcn_sinf(r10) + lam * __builtin_amdgcn_sinf(r20));
        a_s1 += ex * (oml * __builtin_amdgcn_sinf(r11) + lam * __builtin_amdgcn_sinf(r21));
        a_c0 += ex * (oml * __builtin_amdgcn_cosf(r10) + lam * __builtin_amdgcn_cosf(r20));
        a_c1 += ex * (oml * __builtin_amdgcn_cosf(r11) + lam * __builtin_amdgcn_cosf(r21));
        if (l < 5) {
            int si = src[e];
            f32x2 xs = *(const f32x2*)&X_msg[si * 2];
            float lead = (l == 0) ? xs[0] : (l == 1) ? xs[1]
                       : (l == 2) ? f4[0] : (l == 3) ? dt : f4[2];
            a_lead += ex * lead;
        }
    }
    float inv = (denom > 0.0f) ? 1.0f / denom : 0.0f;
    float* row = h_att + (size_t)node * MSG_DIM;
    if (l < 5) row[l] = a_lead * inv;
    row[5 + k0]      = a_s0 * inv;
    row[5 + k1]      = a_s1 * inv;
    row[5 + DD + k0] = a_c0 * inv;
    row[5 + DD + k1] = a_c1 * inv;
}

// ---------------- MFMA fused 3-layer MLP ----------------

__global__ void __launch_bounds__(256) k_mlp_mfma(
    const float* __restrict__ h_att,
    const short* __restrict__ pk1, const float* __restrict__ b1,
    const short* __restrict__ pk2, const float* __restrict__ b2,
    const short* __restrict__ pk3, const float* __restrict__ b3,
    float* __restrict__ out, int n)
{
    __shared__ float lds[64 * 132];
    int wave = threadIdx.x >> 6;
    int lane = threadIdx.x & 63;
    int block0 = blockIdx.x * 64;

    for (int idx = threadIdx.x; idx < 64 * 96; idx += 256) {
        int r = idx / 96, c = idx - r * 96;
        int node = block0 + r;
        lds[r * 132 + c] = (c < MSG_DIM && node < n) ? h_att[(size_t)node * MSG_DIM + c] : 0.0f;
    }
    __syncthreads();

    const int R = wave * 16;
    const int arow = R + (lane & 15);
    const int kbase = (lane >> 4) * 8;
    const int ccol = lane & 15;
    const int crow0 = (lane >> 4) * 4;

    auto run_layer = [&](const short* __restrict__ pk, const float* __restrict__ bias,
                         int S, bool last) {
        f32x4 acc[8];
#pragma unroll
        for (int t = 0; t < 8; t++) acc[t] = (f32x4){0.f, 0.f, 0.f, 0.f};
        const int plane = 8 * S * 512;
        for (int s = 0; s < S; s++) {
            const float* ap = &lds[arow * 132 + 32 * s + kbase];
            f32x4 av0 = *(const f32x4*)ap;
            f32x4 av1 = *(const f32x4*)(ap + 4);
            float av[8] = {av0[0], av0[1], av0[2], av0[3], av1[0], av1[1], av1[2], av1[3]};
            bf16x8 ah, al;
            pack_split_rne(av, ah, al);
#pragma unroll
            for (int t = 0; t < 8; t++) {
                const short* bp = pk + ((size_t)(t * S + s) * 64 + lane) * 8;
                bf16x8 bh = *(const bf16x8*)bp;
                bf16x8 bl = *(const bf16x8*)(bp + plane);
                acc[t] = __builtin_amdgcn_mfma_f32_16x16x32_bf16(ah, bh, acc[t], 0, 0, 0);
                acc[t] = __builtin_amdgcn_mfma_f32_16x16x32_bf16(ah, bl, acc[t], 0, 0, 0);
                acc[t] = __builtin_amdgcn_mfma_f32_16x16x32_bf16(al, bh, acc[t], 0, 0, 0);
            }
        }
        __syncthreads();
#pragma unroll
        for (int t = 0; t < 8; t++) {
            float b = bias[16 * t + ccol];
#pragma unroll
            for (int r = 0; r < 4; r++) {
                float v = fmaxf(acc[t][r] + b, 0.0f);
                int row = R + crow0 + r;
                if (!last) {
                    lds[row * 132 + 16 * t + ccol] = v;
                } else {
                    int node = block0 + row;
                    if (node < n) out[(size_t)node * NHID + 16 * t + ccol] = v;
                }
            }
        }
        __syncthreads();
    };

    run_layer(pk1, b1, 3, false);
    run_layer(pk2, b2, 4, false);
    run_layer(pk3, b3, 4, true);
}

extern "C" void kernel_launch(void* const* d_in, const int* in_sizes, int n_in,
                              void* d_out, int out_size, void* d_ws, size_t ws_size,
                              hipStream_t stream)
{
    const float* X_msg    = (const float*)d_in[0];
    const float* feature  = (const float*)d_in[1];
    const float* te_w     = (const float*)d_in[2];
    const float* te_lam   = (const float*)d_in[3];
    const float* shared_w = (const float*)d_in[4];
    const float* shared_b = (const float*)d_in[5];
    const float* w_att_w  = (const float*)d_in[6];
    const float* w_att_b  = (const float*)d_in[7];
    const float* va       = (const float*)d_in[8];
    const float* w1       = (const float*)d_in[9];
    const float* b1       = (const float*)d_in[10];
    const float* w2       = (const float*)d_in[11];
    const float* b2       = (const float*)d_in[12];
    const float* w3       = (const float*)d_in[13];
    const float* b3       = (const float*)d_in[14];
    const int*   src      = (const int*)d_in[15];
    const int*   dst      = (const int*)d_in[16];
    const int*   dst_lane = (const int*)d_in[17];
    float* out = (float*)d_out;

    int N = in_sizes[0] / 2;   // X_msg (N,2)
    int E = in_sizes[15];      // src (E,)

    // workspace layout (4-byte units)
    float* att_perm = (float*)d_ws;              // E (fallback path only)
    int*   edge_ids = (int*)(att_perm + E);      // E
    int*   perm     = edge_ids + E;              // E
    int*   offs     = perm + E;                  // N+1
    int*   woff     = offs + N + 1;              // N
    int*   counts   = woff + N;                  // N
    int*   bsums    = counts + N;                // 128
    float* h_att    = (float*)(bsums + 128);     // N*MSG_DIM
    short* pk1      = (short*)(h_att + (size_t)N * MSG_DIM);  // 24576 shorts
    short* pk2      = pk1 + 24576;                            // 32768 shorts
    short* pk3      = pk2 + 32768;                            // 32768 shorts
    short* pk_att   = pk3 + 32768;                            // 24576 shorts
    // 32B-align the record array
    size_t rec_off = (((size_t)((char*)(pk_att + 24576) - (char*)d_ws)) + 31) & ~(size_t)31;
    float* rec8    = (float*)((char*)d_ws + rec_off);         // E*8 floats

    size_t need = rec_off + (size_t)E * 8 * sizeof(float);
    int streams_ok = (ws_size >= need) ? 1 : 0;

    int ng = (N + 255) / 256;
    int eg = (E + 255) / 256;
    int nb = (N + SCAN_BLK - 1) / SCAN_BLK;

    hipMemsetAsync(counts, 0, (size_t)N * sizeof(int), stream);
    k_hist<<<eg, 256, 0, stream>>>(dst, counts, E);
    k_scan1<<<nb, 256, 0, stream>>>(counts, offs, bsums, N);
    k_scan2p<<<1, 128, 0, stream>>>(bsums, nb);
    k_scan3<<<ng, 256, 0, stream>>>(offs, woff, bsums, N, E);
    k_fill<<<eg, 256, 0, stream>>>(dst, woff, edge_ids, perm, E);

    k_prep<<<(57344 + 255) / 256, 256, 0, stream>>>(w1, w2, w3, w_att_w,
                                                    pk1, pk2, pk3, pk_att);

    k_att_mfma<<<(E + 63) / 64, 256, 0, stream>>>(
        X_msg, feature, te_w, te_lam, shared_w, shared_b,
        pk_att, w_att_b, va, src, dst, dst_lane, perm, att_perm,
        rec8, streams_ok, E);

    if (streams_ok) {
        k_gather_stream<<<(N + 15) / 16, 256, 0, stream>>>(
            te_w, te_lam, shared_w, shared_b, rec8, offs, h_att, N);
    } else {
        k_gather_wave<<<(N + 15) / 16, 256, 0, stream>>>(
            X_msg, feature, te_w, te_lam, shared_w, shared_b, src, dst_lane,
            att_perm, offs, edge_ids, h_att, N);
    }

    k_mlp_mfma<<<(N + 63) / 64, 256, 0, stream>>>(h_att, pk1, b1, pk2, b2, pk3, b3, out, N);
}

// Round 22
// 622.445 us; speedup vs baseline: 1.7638x; 1.7638x over previous
//
#include <hip/hip_runtime.h>

#define DD      32
#define TE_DIM  64
#define NHID    128
#define XA_DIM  71   // 2 (src) + 2 (dst) + 3 (feat) + 64 (te)
#define MSG_DIM 69   // 2 (src) + 3 (feat) + 64 (te)
#define SCAN_BLK 1024
#define INV2PI  0.15915494309189535f
#define TWO_LOG2E 2.885390081777927f   // 2*log2(e)

typedef __attribute__((ext_vector_type(8))) short bf16x8;
typedef __attribute__((ext_vector_type(4))) float f32x4;
typedef __attribute__((ext_vector_type(2))) float f32x2;
typedef __attribute__((ext_vector_type(4))) unsigned int u32x4;

__device__ __forceinline__ float fast_tanh(float x) {
    return 1.0f - 2.0f / (__builtin_amdgcn_exp2f(x * TWO_LOG2E) + 1.0f);
}

__device__ __forceinline__ unsigned short f32_to_bf16(float x) {
    unsigned u = __float_as_uint(x);
    unsigned r = (u + 0x7FFF + ((u >> 16) & 1)) >> 16;   // RNE, finite inputs
    return (unsigned short)r;
}
__device__ __forceinline__ float bf16_to_f32(unsigned short h) {
    return __uint_as_float(((unsigned)h) << 16);
}

// RNE-hi split pack: hi = rne_bf16(v), lo = trunc_bf16(v - hi). lo absorbs the
// rounding residual exactly -> 3-product MFMA accuracy ~f32.
__device__ __forceinline__ void pack_split_rne(const float* av, bf16x8& hi, bf16x8& lo) {
    union { u32x4 u; bf16x8 b; } H, L;
#pragma unroll
    for (int p = 0; p < 4; p++) {
        unsigned ua = __float_as_uint(av[2 * p]);
        unsigned ub = __float_as_uint(av[2 * p + 1]);
        unsigned ra = ua + 0x7FFF + ((ua >> 16) & 1);
        unsigned rb = ub + 0x7FFF + ((ub >> 16) & 1);
        H.u[p] = __builtin_amdgcn_perm(rb, ra, 0x07060302);
        float la = av[2 * p]     - __uint_as_float(ra & 0xFFFF0000u);
        float lb = av[2 * p + 1] - __uint_as_float(rb & 0xFFFF0000u);
        L.u[p] = __builtin_amdgcn_perm(__float_as_uint(lb), __float_as_uint(la), 0x07060302);
    }
    hi = H.b;
    lo = L.b;
}

// ---------------- CSR build ----------------

__global__ void k_hist(const int* __restrict__ dst, int* __restrict__ counts, int E) {
    int e = blockIdx.x * blockDim.x + threadIdx.x;
    if (e < E) atomicAdd(&counts[dst[e]], 1);
}

__global__ void __launch_bounds__(256) k_scan1(
    const int* __restrict__ counts, int* __restrict__ offs,
    int* __restrict__ bsums, int n)
{
    __shared__ int lds[256];
    int t = threadIdx.x;
    int base = blockIdx.x * SCAN_BLK + t * 4;
    int v[4]; int tsum = 0;
#pragma unroll
    for (int i = 0; i < 4; i++) { v[i] = (base + i < n) ? counts[base + i] : 0; tsum += v[i]; }
    lds[t] = tsum;
    __syncthreads();
    for (int off = 1; off < 256; off <<= 1) {
        int x = (t >= off) ? lds[t - off] : 0;
        __syncthreads();
        lds[t] += x;
        __syncthreads();
    }
    int excl = lds[t] - tsum;
    if (t == 255) bsums[blockIdx.x] = lds[255];
    int run = excl;
#pragma unroll
    for (int i = 0; i < 4; i++) {
        if (base + i < n) offs[base + i] = run;
        run += v[i];
    }
}

// single-block parallel exclusive scan of nb (<=128) block sums
__global__ void __launch_bounds__(128) k_scan2p(int* bsums, int nb) {
    __shared__ int lds[128];
    int t = threadIdx.x;
    int v = (t < nb) ? bsums[t] : 0;
    lds[t] = v;
    __syncthreads();
    for (int off = 1; off < 128; off <<= 1) {
        int x = (t >= off) ? lds[t - off] : 0;
        __syncthreads();
        lds[t] += x;
        __syncthreads();
    }
    if (t < nb) bsums[t] = lds[t] - v;
}

__global__ void k_scan3(int* __restrict__ offs, int* __restrict__ woff,
                        const int* __restrict__ bsums, int n, int E)
{
    int i = blockIdx.x * blockDim.x + threadIdx.x;
    if (i < n) {
        int v = offs[i] + bsums[i >> 10];
        offs[i] = v;
        woff[i] = v;
        if (i == 0) offs[n] = E;
    }
}

__global__ void k_fill(const int* __restrict__ dst, int* __restrict__ woff,
                       int* __restrict__ edge_ids, int* __restrict__ perm, int E)
{
    int e = blockIdx.x * blockDim.x + threadIdx.x;
    if (e < E) {
        int pos = atomicAdd(&woff[dst[e]], 1);
        edge_ids[pos] = e;
        perm[e] = pos;
    }
}

// ---------------- weight pre-pack into MFMA B-fragment layout ----------------

__global__ void k_prep(const float* __restrict__ w1, const float* __restrict__ w2,
                       const float* __restrict__ w3, const float* __restrict__ watt,
                       short* __restrict__ pk1, short* __restrict__ pk2,
                       short* __restrict__ pk3, short* __restrict__ pkatt)
{
    int idx = blockIdx.x * blockDim.x + threadIdx.x;
    const float* w; short* pk; int S, K, li;
    if (idx < 12288)              { w = w1;   pk = pk1;   S = 3; K = 69;  li = idx; }
    else if (idx < 28672)         { w = w2;   pk = pk2;   S = 4; K = 128; li = idx - 12288; }
    else if (idx < 45056)         { w = w3;   pk = pk3;   S = 4; K = 128; li = idx - 28672; }
    else if (idx < 57344)         { w = watt; pk = pkatt; S = 3; K = 71;  li = idx - 45056; }
    else return;
    int i    = li & 7;
    int lane = (li >> 3) & 63;
    int ts   = li >> 9;            // t*S + s
    int s = ts % S, t = ts / S;
    int col = 16 * t + (lane & 15);
    int k   = 32 * s + (lane >> 4) * 8 + i;
    float v = (k < K) ? w[col * K + k] : 0.0f;
    unsigned short hi = f32_to_bf16(v);
    float lo = v - bf16_to_f32(hi);
    int plane = 8 * S * 512;
    pk[li]         = (short)hi;
    pk[li + plane] = (short)f32_to_bf16(lo);
}

// ---------------- MFMA attention logits ----------------
// 64 edges/block, 4 waves; wave w owns rows [16w,16w+16), 1 A-row per thread.
// Native v_sin/v_cos trig, RNE split-pack fragments, global B reads.
// Epilogue att routed through a 64-float LDS buffer (cheaper in VGPR than the
// 4-shfl routing); NO min-waves launch bound (R21: forcing 8 waves/SIMD
// spilled to scratch, 2.9GB HBM traffic -> 854us). Allocator chooses VGPR.
// store_streams: one 32B record per edge at CSR slot perm[e].

__global__ void __launch_bounds__(256) k_att_mfma(
    const float* __restrict__ X_msg, const float* __restrict__ feature,
    const float* __restrict__ te_w, const float* __restrict__ te_lam,
    const float* __restrict__ shared_w, const float* __restrict__ shared_b,
    const short* __restrict__ pk_att, const float* __restrict__ w_att_b,
    const float* __restrict__ va,
    const int* __restrict__ src, const int* __restrict__ dst,
    const int* __restrict__ dst_lane,
    const int* __restrict__ perm, float* __restrict__ att_perm,
    float* __restrict__ rec8, int store_streams, int E)
{
    __shared__ float rowv[7][64];    // xs0,xs1,xd0,xd1,f0,dt,f2 (SoA)
    __shared__ float attS[64];
    __shared__ int   lns[64];
    __shared__ float lam8[8];
    __shared__ float twr[8][33];     // te_w * INV2PI, padded
    __shared__ float swr[32], sbr[32];

    int tid = threadIdx.x;
    int wave = tid >> 6, lane = tid & 63;
    int block0 = blockIdx.x * 64;

    twr[tid >> 5][tid & 31] = te_w[tid] * INV2PI;       // 256 = 8*32
    if (tid < 32) { swr[tid] = shared_w[tid] * INV2PI; sbr[tid] = shared_b[tid] * INV2PI; }
    if (tid < 8)  { float rl = te_lam[tid]; lam8[tid] = __expf(-rl * rl); }
    if (tid < 64) {
        int e = block0 + tid;
        if (e < E) {
            int s = src[e], d = dst[e];
            f32x4 f4 = *(const f32x4*)&feature[e * 4];
            f32x2 xs = *(const f32x2*)&X_msg[s * 2];
            f32x2 xd = *(const f32x2*)&X_msg[d * 2];
            rowv[0][tid] = xs[0]; rowv[1][tid] = xs[1];
            rowv[2][tid] = xd[0]; rowv[3][tid] = xd[1];
            rowv[4][tid] = f4[0]; rowv[5][tid] = f4[1]; rowv[6][tid] = f4[2];
            lns[tid] = dst_lane[e];
        } else {
#pragma unroll
            for (int c = 0; c < 7; c++) rowv[c][tid] = 0.0f;
            lns[tid] = 0;
        }
    }
    __syncthreads();

    const int R = wave * 16;
    const int rlo = lane & 15;
    const int r0 = R + rlo;
    const int g = lane >> 4;
    const int kbase = g * 8;
    int e_row = block0 + r0;

    float dt = rowv[5][r0];
    int ln = lns[r0];
    float lam = lam8[ln], oml = 1.0f - lam;

    float tes[8], tec[8];
#pragma unroll
    for (int i = 0; i < 8; i++) {
        int k = (kbase + i + 25) & 31;
        float rev1 = dt * twr[ln][k];
        float rev2 = fmaf(dt, swr[k], sbr[k]);
        float s1 = __builtin_amdgcn_sinf(rev1), c1 = __builtin_amdgcn_cosf(rev1);
        float s2 = __builtin_amdgcn_sinf(rev2), c2 = __builtin_amdgcn_cosf(rev2);
        tes[i] = oml * s1 + lam * s2;
        tec[i] = oml * c1 + lam * c2;
    }

    f32x4 acc[8];
#pragma unroll
    for (int t = 0; t < 8; t++) acc[t] = (f32x4){0.f, 0.f, 0.f, 0.f};

#pragma unroll
    for (int s = 0; s < 3; s++) {
        float av[8];
#pragma unroll
        for (int i = 0; i < 8; i++) {
            int c = 32 * s + kbase + i;
            if (s == 0)      av[i] = (c < 7)  ? rowv[c][r0] : tes[i];
            else if (s == 1) av[i] = (c < 39) ? tes[i] : tec[i];
            else             av[i] = (c < 71) ? tec[i] : 0.0f;
        }
        bf16x8 ah, al;
        pack_split_rne(av, ah, al);
#pragma unroll
        for (int t = 0; t < 8; t++) {
            const short* bp = pk_att + ((t * 3 + s) * 64 + lane) * 8;
            bf16x8 bh = *(const bf16x8*)bp;
            bf16x8 bl = *(const bf16x8*)(bp + 12288);
            acc[t] = __builtin_amdgcn_mfma_f32_16x16x32_bf16(ah, bh, acc[t], 0, 0, 0);
            acc[t] = __builtin_amdgcn_mfma_f32_16x16x32_bf16(ah, bl, acc[t], 0, 0, 0);
            acc[t] = __builtin_amdgcn_mfma_f32_16x16x32_bf16(al, bh, acc[t], 0, 0, 0);
        }
    }

    // epilogue: att_row = sum_j va[j] * tanh(pre[j] + b[j])
    int ccol = lane & 15;
    float sums[4] = {0.f, 0.f, 0.f, 0.f};
#pragma unroll
    for (int t = 0; t < 8; t++) {
        float b = w_att_b[16 * t + ccol];
        float v = va[16 * t + ccol];
#pragma unroll
        for (int r = 0; r < 4; r++)
            sums[r] += v * fast_tanh(acc[t][r] + b);
    }
#pragma unroll
    for (int mask = 1; mask < 16; mask <<= 1)
#pragma unroll
        for (int r = 0; r < 4; r++)
            sums[r] += __shfl_xor(sums[r], mask);
    // sums[r] uniform across each 16-lane group; group g holds edges R+4g+r.

    if (store_streams) {
        int q = lane & 15;
        if (q < 4) attS[R + 4 * g + q] = sums[q];
        __syncthreads();
        if (g == 0 && e_row < E) {
            int pe = perm[e_row];
            f32x4 rc0 = {rowv[0][r0], rowv[1][r0], rowv[4][r0], rowv[6][r0]};
            f32x4 rc1 = {dt, __int_as_float(ln), attS[r0], 0.0f};
            *(f32x4*)&rec8[(size_t)pe * 8]     = rc0;
            *(f32x4*)&rec8[(size_t)pe * 8 + 4] = rc1;
        }
    } else {
        int q = lane & 15;
        if (q < 4) {
            int e2 = block0 + R + 4 * g + q;
            if (e2 < E) att_perm[perm[e2]] = sums[q];
        }
    }
}

// ---------------- streaming wave-split gather (32B records, slot order) -----

__global__ void __launch_bounds__(256) k_gather_stream(
    const float* __restrict__ te_w, const float* __restrict__ te_lam,
    const float* __restrict__ shared_w, const float* __restrict__ shared_b,
    const float* __restrict__ rec8,
    const int* __restrict__ offs, float* __restrict__ h_att, int n)
{
    __shared__ float twr[8][33];
    __shared__ float swr[32], sbr[32];
    __shared__ float lam8[8];
    int tid = threadIdx.x;
    twr[tid >> 5][tid & 31] = te_w[tid] * INV2PI;
    if (tid < 32) { swr[tid] = shared_w[tid] * INV2PI; sbr[tid] = shared_b[tid] * INV2PI; }
    if (tid < 8)  { float rl = te_lam[tid]; lam8[tid] = __expf(-rl * rl); }
    __syncthreads();

    int node = blockIdx.x * 16 + (tid >> 4);
    int l = tid & 15;
    if (node >= n) return;
    int beg = offs[node], end = offs[node + 1];

    float mx = -INFINITY;
    for (int slot = beg + l; slot < end; slot += 16)
        mx = fmaxf(mx, rec8[(size_t)slot * 8 + 6]);
#pragma unroll
    for (int m = 1; m < 16; m <<= 1)
        mx = fmaxf(mx, __shfl_xor(mx, m, 16));

    const int k0 = 2 * l, k1 = k0 + 1;
    const float sw0 = swr[k0], sb0 = sbr[k0];
    const float sw1 = swr[k1], sb1 = sbr[k1];

    float a_s0 = 0.f, a_s1 = 0.f, a_c0 = 0.f, a_c1 = 0.f, a_lead = 0.f, denom = 0.f;
    for (int slot = beg; slot < end; slot++) {
        f32x4 rc1 = *(const f32x4*)&rec8[(size_t)slot * 8 + 4];
        float dt = rc1[0];
        int ln = __float_as_int(rc1[1]);
        float ex = __expf(rc1[2] - mx);
        denom += ex;
        float lam = lam8[ln], oml = 1.0f - lam;
        float r10 = dt * twr[ln][k0];
        float r11 = dt * twr[ln][k1];
        float r20 = fmaf(dt, sw0, sb0);
        float r21 = fmaf(dt, sw1, sb1);
        a_s0 += ex * (oml * __builtin_amdgcn_sinf(r10) + lam * __builtin_amdgcn_sinf(r20));
        a_s1 += ex * (oml * __builtin_amdgcn_sinf(r11) + lam * __builtin_amdgcn_sinf(r21));
        a_c0 += ex * (oml * __builtin_amdgcn_cosf(r10) + lam * __builtin_amdgcn_cosf(r20));
        a_c1 += ex * (oml * __builtin_amdgcn_cosf(r11) + lam * __builtin_amdgcn_cosf(r21));
        if (l < 5) {
            f32x4 rc0 = *(const f32x4*)&rec8[(size_t)slot * 8];
            float lead = (l == 0) ? rc0[0] : (l == 1) ? rc0[1]
                       : (l == 2) ? rc0[2] : (l == 3) ? dt : rc0[3];
            a_lead += ex * lead;
        }
    }
    float inv = (denom > 0.0f) ? 1.0f / denom : 0.0f;
    float* row = h_att + (size_t)node * MSG_DIM;
    if (l < 5) row[l] = a_lead * inv;
    row[5 + k0]      = a_s0 * inv;
    row[5 + k1]      = a_s1 * inv;
    row[5 + DD + k0] = a_c0 * inv;
    row[5 + DD + k1] = a_c1 * inv;
}

// ---------------- fallback gather (used if ws too small) -------

__global__ void __launch_bounds__(256) k_gather_wave(
    const float* __restrict__ X_msg, const float* __restrict__ feature,
    const float* __restrict__ te_w, const float* __restrict__ te_lam,
    const float* __restrict__ shared_w, const float* __restrict__ shared_b,
    const int* __restrict__ src, const int* __restrict__ dst_lane,
    const float* __restrict__ att_perm,
    const int* __restrict__ offs, const int* __restrict__ edge_ids,
    float* __restrict__ h_att, int n)
{
    __shared__ float twr[8][33];
    __shared__ float swr[32], sbr[32];
    __shared__ float lam8[8];
    int tid = threadIdx.x;
    twr[tid >> 5][tid & 31] = te_w[tid] * INV2PI;
    if (tid < 32) { swr[tid] = shared_w[tid] * INV2PI; sbr[tid] = shared_b[tid] * INV2PI; }
    if (tid < 8)  { float rl = te_lam[tid]; lam8[tid] = __expf(-rl * rl); }
    __syncthreads();

    int node = blockIdx.x * 16 + (tid >> 4);
    int l = tid & 15;
    if (node >= n) return;
    int beg = offs[node], end = offs[node + 1];

    float mx = -INFINITY;
    for (int slot = beg + l; slot < end; slot += 16)
        mx = fmaxf(mx, att_perm[slot]);
#pragma unroll
    for (int m = 1; m < 16; m <<= 1)
        mx = fmaxf(mx, __shfl_xor(mx, m, 16));

    const int k0 = 2 * l, k1 = k0 + 1;
    const float sw0 = swr[k0], sb0 = sbr[k0];
    const float sw1 = swr[k1], sb1 = sbr[k1];

    float a_s0 = 0.f, a_s1 = 0.f, a_c0 = 0.f, a_c1 = 0.f, a_lead = 0.f, denom = 0.f;
    for (int slot = beg; slot < end; slot++) {
        int e = edge_ids[slot];
        float ex = __expf(att_perm[slot] - mx);
        denom += ex;
        int ln = dst_lane[e];
        f32x4 f4 = *(const f32x4*)&feature[e * 4];
        float dt = f4[1];
        float lam = lam8[ln], oml = 1.0f - lam;
        float r10 = dt * twr[ln][k0];
        float r11 = dt * twr[ln][k1];
        float r20 = fmaf(dt, sw0, sb0);
        float r21 = fmaf(dt, sw1, sb1);
        a_s0 += ex * (oml * __builtin_amdgcn_sinf(r10) + lam * __builtin_amdgcn_sinf(r20));
        a_s1 += ex * (oml * __builtin_amdgcn_sinf(r11) + lam * __builtin_amdgcn_sinf(r21));
        a_c0 += ex * (oml * __builtin_amdgcn_cosf(r10) + lam * __builtin_amdgcn_cosf(r20));
        a_c1 += ex * (oml * __builtin_amdgcn_cosf(r11) + lam * __builtin_amdgcn_cosf(r21));
        if (l < 5) {
            int si = src[e];
            f32x2 xs = *(const f32x2*)&X_msg[si * 2];
            float lead = (l == 0) ? xs[0] : (l == 1) ? xs[1]
                       : (l == 2) ? f4[0] : (l == 3) ? dt : f4[2];
            a_lead += ex * lead;
        }
    }
    float inv = (denom > 0.0f) ? 1.0f / denom : 0.0f;
    float* row = h_att + (size_t)node * MSG_DIM;
    if (l < 5) row[l] = a_lead * inv;
    row[5 + k0]      = a_s0 * inv;
    row[5 + k1]      = a_s1 * inv;
    row[5 + DD + k0] = a_c0 * inv;
    row[5 + DD + k1] = a_c1 * inv;
}

// ---------------- MFMA fused 3-layer MLP ----------------

__global__ void __launch_bounds__(256) k_mlp_mfma(
    const float* __restrict__ h_att,
    const short* __restrict__ pk1, const float* __restrict__ b1,
    const short* __restrict__ pk2, const float* __restrict__ b2,
    const short* __restrict__ pk3, const float* __restrict__ b3,
    float* __restrict__ out, int n)
{
    __shared__ float lds[64 * 132];
    int wave = threadIdx.x >> 6;
    int lane = threadIdx.x & 63;
    int block0 = blockIdx.x * 64;

    for (int idx = threadIdx.x; idx < 64 * 96; idx += 256) {
        int r = idx / 96, c = idx - r * 96;
        int node = block0 + r;
        lds[r * 132 + c] = (c < MSG_DIM && node < n) ? h_att[(size_t)node * MSG_DIM + c] : 0.0f;
    }
    __syncthreads();

    const int R = wave * 16;
    const int arow = R + (lane & 15);
    const int kbase = (lane >> 4) * 8;
    const int ccol = lane & 15;
    const int crow0 = (lane >> 4) * 4;

    auto run_layer = [&](const short* __restrict__ pk, const float* __restrict__ bias,
                         int S, bool last) {
        f32x4 acc[8];
#pragma unroll
        for (int t = 0; t < 8; t++) acc[t] = (f32x4){0.f, 0.f, 0.f, 0.f};
        const int plane = 8 * S * 512;
        for (int s = 0; s < S; s++) {
            const float* ap = &lds[arow * 132 + 32 * s + kbase];
            f32x4 av0 = *(const f32x4*)ap;
            f32x4 av1 = *(const f32x4*)(ap + 4);
            float av[8] = {av0[0], av0[1], av0[2], av0[3], av1[0], av1[1], av1[2], av1[3]};
            bf16x8 ah, al;
            pack_split_rne(av, ah, al);
#pragma unroll
            for (int t = 0; t < 8; t++) {
                const short* bp = pk + ((size_t)(t * S + s) * 64 + lane) * 8;
                bf16x8 bh = *(const bf16x8*)bp;
                bf16x8 bl = *(const bf16x8*)(bp + plane);
                acc[t] = __builtin_amdgcn_mfma_f32_16x16x32_bf16(ah, bh, acc[t], 0, 0, 0);
                acc[t] = __builtin_amdgcn_mfma_f32_16x16x32_bf16(ah, bl, acc[t], 0, 0, 0);
                acc[t] = __builtin_amdgcn_mfma_f32_16x16x32_bf16(al, bh, acc[t], 0, 0, 0);
            }
        }
        __syncthreads();
#pragma unroll
        for (int t = 0; t < 8; t++) {
            float b = bias[16 * t + ccol];
#pragma unroll
            for (int r = 0; r < 4; r++) {
                float v = fmaxf(acc[t][r] + b, 0.0f);
                int row = R + crow0 + r;
                if (!last) {
                    lds[row * 132 + 16 * t + ccol] = v;
                } else {
                    int node = block0 + row;
                    if (node < n) out[(size_t)node * NHID + 16 * t + ccol] = v;
                }
            }
        }
        __syncthreads();
    };

    run_layer(pk1, b1, 3, false);
    run_layer(pk2, b2, 4, false);
    run_layer(pk3, b3, 4, true);
}

extern "C" void kernel_launch(void* const* d_in, const int* in_sizes, int n_in,
                              void* d_out, int out_size, void* d_ws, size_t ws_size,
                              hipStream_t stream)
{
    const float* X_msg    = (const float*)d_in[0];
    const float* feature  = (const float*)d_in[1];
    const float* te_w     = (const float*)d_in[2];
    const float* te_lam   = (const float*)d_in[3];
    const float* shared_w = (const float*)d_in[4];
    const float* shared_b = (const float*)d_in[5];
    const float* w_att_w  = (const float*)d_in[6];
    const float* w_att_b  = (const float*)d_in[7];
    const float* va       = (const float*)d_in[8];
    const float* w1       = (const float*)d_in[9];
    const float* b1       = (const float*)d_in[10];
    const float* w2       = (const float*)d_in[11];
    const float* b2       = (const float*)d_in[12];
    const float* w3       = (const float*)d_in[13];
    const float* b3       = (const float*)d_in[14];
    const int*   src      = (const int*)d_in[15];
    const int*   dst      = (const int*)d_in[16];
    const int*   dst_lane = (const int*)d_in[17];
    float* out = (float*)d_out;

    int N = in_sizes[0] / 2;   // X_msg (N,2)
    int E = in_sizes[15];      // src (E,)

    // workspace layout (4-byte units)
    float* att_perm = (float*)d_ws;              // E (fallback path only)
    int*   edge_ids = (int*)(att_perm + E);      // E
    int*   perm     = edge_ids + E;              // E
    int*   offs     = perm + E;                  // N+1
    int*   woff     = offs + N + 1;              // N
    int*   counts   = woff + N;                  // N
    int*   bsums    = counts + N;                // 128
    float* h_att    = (float*)(bsums + 128);     // N*MSG_DIM
    short* pk1      = (short*)(h_att + (size_t)N * MSG_DIM);  // 24576 shorts
    short* pk2      = pk1 + 24576;                            // 32768 shorts
    short* pk3      = pk2 + 32768;                            // 32768 shorts
    short* pk_att   = pk3 + 32768;                            // 24576 shorts
    // 32B-align the record array
    size_t rec_off = (((size_t)((char*)(pk_att + 24576) - (char*)d_ws)) + 31) & ~(size_t)31;
    float* rec8    = (float*)((char*)d_ws + rec_off);         // E*8 floats

    size_t need = rec_off + (size_t)E * 8 * sizeof(float);
    int streams_ok = (ws_size >= need) ? 1 : 0;

    int ng = (N + 255) / 256;
    int eg = (E + 255) / 256;
    int nb = (N + SCAN_BLK - 1) / SCAN_BLK;

    hipMemsetAsync(counts, 0, (size_t)N * sizeof(int), stream);
    k_hist<<<eg, 256, 0, stream>>>(dst, counts, E);
    k_scan1<<<nb, 256, 0, stream>>>(counts, offs, bsums, N);
    k_scan2p<<<1, 128, 0, stream>>>(bsums, nb);
    k_scan3<<<ng, 256, 0, stream>>>(offs, woff, bsums, N, E);
    k_fill<<<eg, 256, 0, stream>>>(dst, woff, edge_ids, perm, E);

    k_prep<<<(57344 + 255) / 256, 256, 0, stream>>>(w1, w2, w3, w_att_w,
                                                    pk1, pk2, pk3, pk_att);

    k_att_mfma<<<(E + 63) / 64, 256, 0, stream>>>(
        X_msg, feature, te_w, te_lam, shared_w, shared_b,
        pk_att, w_att_b, va, src, dst, dst_lane, perm, att_perm,
        rec8, streams_ok, E);

    if (streams_ok) {
        k_gather_stream<<<(N + 15) / 16, 256, 0, stream>>>(
            te_w, te_lam, shared_w, shared_b, rec8, offs, h_att, N);
    } else {
        k_gather_wave<<<(N + 15) / 16, 256, 0, stream>>>(
            X_msg, feature, te_w, te_lam, shared_w, shared_b, src, dst_lane,
            att_perm, offs, edge_ids, h_att, N);
    }

    k_mlp_mfma<<<(N + 63) / 64, 256, 0, stream>>>(h_att, pk1, b1, pk2, b2, pk3, b3, out, N);
}

// Round 25
// 549.572 us; speedup vs baseline: 1.9976x; 1.1326x over previous
//
#include <hip/hip_runtime.h>

#define DD      32
#define TE_DIM  64
#define NHID    128
#define XA_DIM  71   // 2 (src) + 2 (dst) + 3 (feat) + 64 (te)
#define MSG_DIM 69   // 2 (src) + 3 (feat) + 64 (te)
#define SCAN_BLK 1024
#define INV2PI  0.15915494309189535f
#define TWO_LOG2E 2.885390081777927f   // 2*log2(e)

typedef __attribute__((ext_vector_type(8))) short bf16x8;
typedef __attribute__((ext_vector_type(4))) float f32x4;
typedef __attribute__((ext_vector_type(2))) float f32x2;
typedef __attribute__((ext_vector_type(4))) unsigned int u32x4;

__device__ __forceinline__ float fast_tanh(float x) {
    return 1.0f - 2.0f / (__builtin_amdgcn_exp2f(x * TWO_LOG2E) + 1.0f);
}

__device__ __forceinline__ unsigned short f32_to_bf16(float x) {
    unsigned u = __float_as_uint(x);
    unsigned r = (u + 0x7FFF + ((u >> 16) & 1)) >> 16;   // RNE, finite inputs
    return (unsigned short)r;
}
__device__ __forceinline__ float bf16_to_f32(unsigned short h) {
    return __uint_as_float(((unsigned)h) << 16);
}

// RNE-hi split pack: hi = rne_bf16(v), lo = trunc_bf16(v - hi). lo absorbs the
// rounding residual exactly -> 3-product MFMA accuracy ~f32.
__device__ __forceinline__ void pack_split_rne(const float* av, bf16x8& hi, bf16x8& lo) {
    union { u32x4 u; bf16x8 b; } H, L;
#pragma unroll
    for (int p = 0; p < 4; p++) {
        unsigned ua = __float_as_uint(av[2 * p]);
        unsigned ub = __float_as_uint(av[2 * p + 1]);
        unsigned ra = ua + 0x7FFF + ((ua >> 16) & 1);
        unsigned rb = ub + 0x7FFF + ((ub >> 16) & 1);
        H.u[p] = __builtin_amdgcn_perm(rb, ra, 0x07060302);
        float la = av[2 * p]     - __uint_as_float(ra & 0xFFFF0000u);
        float lb = av[2 * p + 1] - __uint_as_float(rb & 0xFFFF0000u);
        L.u[p] = __builtin_amdgcn_perm(__float_as_uint(lb), __float_as_uint(la), 0x07060302);
    }
    hi = H.b;
    lo = L.b;
}

// ---------------- CSR build ----------------

__global__ void k_hist(const int* __restrict__ dst, int* __restrict__ counts, int E) {
    int e = blockIdx.x * blockDim.x + threadIdx.x;
    if (e < E) atomicAdd(&counts[dst[e]], 1);
}

__global__ void __launch_bounds__(256) k_scan1(
    const int* __restrict__ counts, int* __restrict__ offs,
    int* __restrict__ bsums, int n)
{
    __shared__ int lds[256];
    int t = threadIdx.x;
    int base = blockIdx.x * SCAN_BLK + t * 4;
    int v[4]; int tsum = 0;
#pragma unroll
    for (int i = 0; i < 4; i++) { v[i] = (base + i < n) ? counts[base + i] : 0; tsum += v[i]; }
    lds[t] = tsum;
    __syncthreads();
    for (int off = 1; off < 256; off <<= 1) {
        int x = (t >= off) ? lds[t - off] : 0;
        __syncthreads();
        lds[t] += x;
        __syncthreads();
    }
    int excl = lds[t] - tsum;
    if (t == 255) bsums[blockIdx.x] = lds[255];
    int run = excl;
#pragma unroll
    for (int i = 0; i < 4; i++) {
        if (base + i < n) offs[base + i] = run;
        run += v[i];
    }
}

// single-block parallel exclusive scan of nb (<=128) block sums
__global__ void __launch_bounds__(128) k_scan2p(int* bsums, int nb) {
    __shared__ int lds[128];
    int t = threadIdx.x;
    int v = (t < nb) ? bsums[t] : 0;
    lds[t] = v;
    __syncthreads();
    for (int off = 1; off < 128; off <<= 1) {
        int x = (t >= off) ? lds[t - off] : 0;
        __syncthreads();
        lds[t] += x;
        __syncthreads();
    }
    if (t < nb) bsums[t] = lds[t] - v;
}

__global__ void k_scan3(int* __restrict__ offs, int* __restrict__ woff,
                        const int* __restrict__ bsums, int n, int E)
{
    int i = blockIdx.x * blockDim.x + threadIdx.x;
    if (i < n) {
        int v = offs[i] + bsums[i >> 10];
        offs[i] = v;
        woff[i] = v;
        if (i == 0) offs[n] = E;
    }
}

// write_eids: the scattered edge_ids write (one 32B sector per edge) is only
// needed by the fallback gather; skipped when the record-stream path is on.
__global__ void k_fill(const int* __restrict__ dst, int* __restrict__ woff,
                       int* __restrict__ edge_ids, int* __restrict__ perm,
                       int write_eids, int E)
{
    int e = blockIdx.x * blockDim.x + threadIdx.x;
    if (e < E) {
        int pos = atomicAdd(&woff[dst[e]], 1);
        if (write_eids) edge_ids[pos] = e;
        perm[e] = pos;
    }
}

// ---------------- weight pre-pack into MFMA B-fragment layout ----------------

__global__ void k_prep(const float* __restrict__ w1, const float* __restrict__ w2,
                       const float* __restrict__ w3, const float* __restrict__ watt,
                       short* __restrict__ pk1, short* __restrict__ pk2,
                       short* __restrict__ pk3, short* __restrict__ pkatt)
{
    int idx = blockIdx.x * blockDim.x + threadIdx.x;
    const float* w; short* pk; int S, K, li;
    if (idx < 12288)              { w = w1;   pk = pk1;   S = 3; K = 69;  li = idx; }
    else if (idx < 28672)         { w = w2;   pk = pk2;   S = 4; K = 128; li = idx - 12288; }
    else if (idx < 45056)         { w = w3;   pk = pk3;   S = 4; K = 128; li = idx - 28672; }
    else if (idx < 57344)         { w = watt; pk = pkatt; S = 3; K = 71;  li = idx - 45056; }
    else return;
    int i    = li & 7;
    int lane = (li >> 3) & 63;
    int ts   = li >> 9;            // t*S + s
    int s = ts % S, t = ts / S;
    int col = 16 * t + (lane & 15);
    int k   = 32 * s + (lane >> 4) * 8 + i;
    float v = (k < K) ? w[col * K + k] : 0.0f;
    unsigned short hi = f32_to_bf16(v);
    float lo = v - bf16_to_f32(hi);
    int plane = 8 * S * 512;
    pk[li]         = (short)hi;
    pk[li + plane] = (short)f32_to_bf16(lo);
}

// ---------------- MFMA attention logits ----------------
// 64 edges/block, 4 waves; wave w owns rows [16w,16w+16), 1 A-row per thread.
// Native v_sin/v_cos trig, RNE split-pack fragments, global B reads.
// ~320us floor at the 4-wave VGPR bracket (R21: forcing 8 waves spills).
// store_streams: one 32B record per edge at CSR slot perm[e].

__global__ void __launch_bounds__(256) k_att_mfma(
    const float* __restrict__ X_msg, const float* __restrict__ feature,
    const float* __restrict__ te_w, const float* __restrict__ te_lam,
    const float* __restrict__ shared_w, const float* __restrict__ shared_b,
    const short* __restrict__ pk_att, const float* __restrict__ w_att_b,
    const float* __restrict__ va,
    const int* __restrict__ src, const int* __restrict__ dst,
    const int* __restrict__ dst_lane,
    const int* __restrict__ perm, float* __restrict__ att_perm,
    float* __restrict__ rec8, int store_streams, int E)
{
    __shared__ float rowv[7][64];    // xs0,xs1,xd0,xd1,f0,dt,f2 (SoA)
    __shared__ float attS[64];
    __shared__ int   lns[64];
    __shared__ float lam8[8];
    __shared__ float twr[8][33];     // te_w * INV2PI, padded
    __shared__ float swr[32], sbr[32];

    int tid = threadIdx.x;
    int wave = tid >> 6, lane = tid & 63;
    int block0 = blockIdx.x * 64;

    twr[tid >> 5][tid & 31] = te_w[tid] * INV2PI;       // 256 = 8*32
    if (tid < 32) { swr[tid] = shared_w[tid] * INV2PI; sbr[tid] = shared_b[tid] * INV2PI; }
    if (tid < 8)  { float rl = te_lam[tid]; lam8[tid] = __expf(-rl * rl); }
    if (tid < 64) {
        int e = block0 + tid;
        if (e < E) {
            int s = src[e], d = dst[e];
            f32x4 f4 = *(const f32x4*)&feature[e * 4];
            f32x2 xs = *(const f32x2*)&X_msg[s * 2];
            f32x2 xd = *(const f32x2*)&X_msg[d * 2];
            rowv[0][tid] = xs[0]; rowv[1][tid] = xs[1];
            rowv[2][tid] = xd[0]; rowv[3][tid] = xd[1];
            rowv[4][tid] = f4[0]; rowv[5][tid] = f4[1]; rowv[6][tid] = f4[2];
            lns[tid] = dst_lane[e];
        } else {
#pragma unroll
            for (int c = 0; c < 7; c++) rowv[c][tid] = 0.0f;
            lns[tid] = 0;
        }
    }
    __syncthreads();

    const int R = wave * 16;
    const int rlo = lane & 15;
    const int r0 = R + rlo;
    const int g = lane >> 4;
    const int kbase = g * 8;
    int e_row = block0 + r0;

    float dt = rowv[5][r0];
    int ln = lns[r0];
    float lam = lam8[ln], oml = 1.0f - lam;

    float tes[8], tec[8];
#pragma unroll
    for (int i = 0; i < 8; i++) {
        int k = (kbase + i + 25) & 31;
        float rev1 = dt * twr[ln][k];
        float rev2 = fmaf(dt, swr[k], sbr[k]);
        float s1 = __builtin_amdgcn_sinf(rev1), c1 = __builtin_amdgcn_cosf(rev1);
        float s2 = __builtin_amdgcn_sinf(rev2), c2 = __builtin_amdgcn_cosf(rev2);
        tes[i] = oml * s1 + lam * s2;
        tec[i] = oml * c1 + lam * c2;
    }

    f32x4 acc[8];
#pragma unroll
    for (int t = 0; t < 8; t++) acc[t] = (f32x4){0.f, 0.f, 0.f, 0.f};

#pragma unroll
    for (int s = 0; s < 3; s++) {
        float av[8];
#pragma unroll
        for (int i = 0; i < 8; i++) {
            int c = 32 * s + kbase + i;
            if (s == 0)      av[i] = (c < 7)  ? rowv[c][r0] : tes[i];
            else if (s == 1) av[i] = (c < 39) ? tes[i] : tec[i];
            else             av[i] = (c < 71) ? tec[i] : 0.0f;
        }
        bf16x8 ah, al;
        pack_split_rne(av, ah, al);
#pragma unroll
        for (int t = 0; t < 8; t++) {
            const short* bp = pk_att + ((t * 3 + s) * 64 + lane) * 8;
            bf16x8 bh = *(const bf16x8*)bp;
            bf16x8 bl = *(const bf16x8*)(bp + 12288);
            acc[t] = __builtin_amdgcn_mfma_f32_16x16x32_bf16(ah, bh, acc[t], 0, 0, 0);
            acc[t] = __builtin_amdgcn_mfma_f32_16x16x32_bf16(ah, bl, acc[t], 0, 0, 0);
            acc[t] = __builtin_amdgcn_mfma_f32_16x16x32_bf16(al, bh, acc[t], 0, 0, 0);
        }
    }

    // epilogue: att_row = sum_j va[j] * tanh(pre[j] + b[j])
    int ccol = lane & 15;
    float sums[4] = {0.f, 0.f, 0.f, 0.f};
#pragma unroll
    for (int t = 0; t < 8; t++) {
        float b = w_att_b[16 * t + ccol];
        float v = va[16 * t + ccol];
#pragma unroll
        for (int r = 0; r < 4; r++)
            sums[r] += v * fast_tanh(acc[t][r] + b);
    }
#pragma unroll
    for (int mask = 1; mask < 16; mask <<= 1)
#pragma unroll
        for (int r = 0; r < 4; r++)
            sums[r] += __shfl_xor(sums[r], mask);
    // sums[r] uniform across each 16-lane group; group g holds edges R+4g+r.

    if (store_streams) {
        int q = lane & 15;
        if (q < 4) attS[R + 4 * g + q] = sums[q];
        __syncthreads();
        if (g == 0 && e_row < E) {
            int pe = perm[e_row];
            f32x4 rc0 = {rowv[0][r0], rowv[1][r0], rowv[4][r0], rowv[6][r0]};
            f32x4 rc1 = {dt, __int_as_float(ln), attS[r0], 0.0f};
            *(f32x4*)&rec8[(size_t)pe * 8]     = rc0;
            *(f32x4*)&rec8[(size_t)pe * 8 + 4] = rc1;
        }
    } else {
        int q = lane & 15;
        if (q < 4) {
            int e2 = block0 + R + 4 * g + q;
            if (e2 < E) att_perm[perm[e2]] = sums[q];
        }
    }
}

// ---------------- streaming wave-split gather (32B records, slot order) -----

__global__ void __launch_bounds__(256) k_gather_stream(
    const float* __restrict__ te_w, const float* __restrict__ te_lam,
    const float* __restrict__ shared_w, const float* __restrict__ shared_b,
    const float* __restrict__ rec8,
    const int* __restrict__ offs, float* __restrict__ h_att, int n)
{
    __shared__ float twr[8][33];
    __shared__ float swr[32], sbr[32];
    __shared__ float lam8[8];
    int tid = threadIdx.x;
    twr[tid >> 5][tid & 31] = te_w[tid] * INV2PI;
    if (tid < 32) { swr[tid] = shared_w[tid] * INV2PI; sbr[tid] = shared_b[tid] * INV2PI; }
    if (tid < 8)  { float rl = te_lam[tid]; lam8[tid] = __expf(-rl * rl); }
    __syncthreads();

    int node = blockIdx.x * 16 + (tid >> 4);
    int l = tid & 15;
    if (node >= n) return;
    int beg = offs[node], end = offs[node + 1];

    float mx = -INFINITY;
    for (int slot = beg + l; slot < end; slot += 16)
        mx = fmaxf(mx, rec8[(size_t)slot * 8 + 6]);
#pragma unroll
    for (int m = 1; m < 16; m <<= 1)
        mx = fmaxf(mx, __shfl_xor(mx, m, 16));

    const int k0 = 2 * l, k1 = k0 + 1;
    const float sw0 = swr[k0], sb0 = sbr[k0];
    const float sw1 = swr[k1], sb1 = sbr[k1];

    float a_s0 = 0.f, a_s1 = 0.f, a_c0 = 0.f, a_c1 = 0.f, a_lead = 0.f, denom = 0.f;
    for (int slot = beg; slot < end; slot++) {
        f32x4 rc1 = *(const f32x4*)&rec8[(size_t)slot * 8 + 4];
        float dt = rc1[0];
        int ln = __float_as_int(rc1[1]);
        float ex = __expf(rc1[2] - mx);
        denom += ex;
        float lam = lam8[ln], oml = 1.0f - lam;
        float r10 = dt * twr[ln][k0];
        float r11 = dt * twr[ln][k1];
        float r20 = fmaf(dt, sw0, sb0);
        float r21 = fmaf(dt, sw1, sb1);
        a_s0 += ex * (oml * __builtin_amdgcn_sinf(r10) + lam * __builtin_amdgcn_sinf(r20));
        a_s1 += ex * (oml * __builtin_amdgcn_sinf(r11) + lam * __builtin_amdgcn_sinf(r21));
        a_c0 += ex * (oml * __builtin_amdgcn_cosf(r10) + lam * __builtin_amdgcn_cosf(r20));
        a_c1 += ex * (oml * __builtin_amdgcn_cosf(r11) + lam * __builtin_amdgcn_cosf(r21));
        if (l < 5) {
            f32x4 rc0 = *(const f32x4*)&rec8[(size_t)slot * 8];
            float lead = (l == 0) ? rc0[0] : (l == 1) ? rc0[1]
                       : (l == 2) ? rc0[2] : (l == 3) ? dt : rc0[3];
            a_lead += ex * lead;
        }
    }
    float inv = (denom > 0.0f) ? 1.0f / denom : 0.0f;
    float* row = h_att + (size_t)node * MSG_DIM;
    if (l < 5) row[l] = a_lead * inv;
    row[5 + k0]      = a_s0 * inv;
    row[5 + k1]      = a_s1 * inv;
    row[5 + DD + k0] = a_c0 * inv;
    row[5 + DD + k1] = a_c1 * inv;
}

// ---------------- fallback gather (used if ws too small) -------

__global__ void __launch_bounds__(256) k_gather_wave(
    const float* __restrict__ X_msg, const float* __restrict__ feature,
    const float* __restrict__ te_w, const float* __restrict__ te_lam,
    const float* __restrict__ shared_w, const float* __restrict__ shared_b,
    const int* __restrict__ src, const int* __restrict__ dst_lane,
    const float* __restrict__ att_perm,
    const int* __restrict__ offs, const int* __restrict__ edge_ids,
    float* __restrict__ h_att, int n)
{
    __shared__ float twr[8][33];
    __shared__ float swr[32], sbr[32];
    __shared__ float lam8[8];
    int tid = threadIdx.x;
    twr[tid >> 5][tid & 31] = te_w[tid] * INV2PI;
    if (tid < 32) { swr[tid] = shared_w[tid] * INV2PI; sbr[tid] = shared_b[tid] * INV2PI; }
    if (tid < 8)  { float rl = te_lam[tid]; lam8[tid] = __expf(-rl * rl); }
    __syncthreads();

    int node = blockIdx.x * 16 + (tid >> 4);
    int l = tid & 15;
    if (node >= n) return;
    int beg = offs[node], end = offs[node + 1];

    float mx = -INFINITY;
    for (int slot = beg + l; slot < end; slot += 16)
        mx = fmaxf(mx, att_perm[slot]);
#pragma unroll
    for (int m = 1; m < 16; m <<= 1)
        mx = fmaxf(mx, __shfl_xor(mx, m, 16));

    const int k0 = 2 * l, k1 = k0 + 1;
    const float sw0 = swr[k0], sb0 = sbr[k0];
    const float sw1 = swr[k1], sb1 = sbr[k1];

    float a_s0 = 0.f, a_s1 = 0.f, a_c0 = 0.f, a_c1 = 0.f, a_lead = 0.f, denom = 0.f;
    for (int slot = beg; slot < end; slot++) {
        int e = edge_ids[slot];
        float ex = __expf(att_perm[slot] - mx);
        denom += ex;
        int ln = dst_lane[e];
        f32x4 f4 = *(const f32x4*)&feature[e * 4];
        float dt = f4[1];
        float lam = lam8[ln], oml = 1.0f - lam;
        float r10 = dt * twr[ln][k0];
        float r11 = dt * twr[ln][k1];
        float r20 = fmaf(dt, sw0, sb0);
        float r21 = fmaf(dt, sw1, sb1);
        a_s0 += ex * (oml * __builtin_amdgcn_sinf(r10) + lam * __builtin_amdgcn_sinf(r20));
        a_s1 += ex * (oml * __builtin_amdgcn_sinf(r11) + lam * __builtin_amdgcn_sinf(r21));
        a_c0 += ex * (oml * __builtin_amdgcn_cosf(r10) + lam * __builtin_amdgcn_cosf(r20));
        a_c1 += ex * (oml * __builtin_amdgcn_cosf(r11) + lam * __builtin_amdgcn_cosf(r21));
        if (l < 5) {
            int si = src[e];
            f32x2 xs = *(const f32x2*)&X_msg[si * 2];
            float lead = (l == 0) ? xs[0] : (l == 1) ? xs[1]
                       : (l == 2) ? f4[0] : (l == 3) ? dt : f4[2];
            a_lead += ex * lead;
        }
    }
    float inv = (denom > 0.0f) ? 1.0f / denom : 0.0f;
    float* row = h_att + (size_t)node * MSG_DIM;
    if (l < 5) row[l] = a_lead * inv;
    row[5 + k0]      = a_s0 * inv;
    row[5 + k1]      = a_s1 * inv;
    row[5 + DD + k0] = a_c0 * inv;
    row[5 + DD + k1] = a_c1 * inv;
}

// ---------------- MFMA fused 3-layer MLP ----------------

__global__ void __launch_bounds__(256) k_mlp_mfma(
    const float* __restrict__ h_att,
    const short* __restrict__ pk1, const float* __restrict__ b1,
    const short* __restrict__ pk2, const float* __restrict__ b2,
    const short* __restrict__ pk3, const float* __restrict__ b3,
    float* __restrict__ out, int n)
{
    __shared__ float lds[64 * 132];
    int wave = threadIdx.x >> 6;
    int lane = threadIdx.x & 63;
    int block0 = blockIdx.x * 64;

    for (int idx = threadIdx.x; idx < 64 * 96; idx += 256) {
        int r = idx / 96, c = idx - r * 96;
        int node = block0 + r;
        lds[r * 132 + c] = (c < MSG_DIM && node < n) ? h_att[(size_t)node * MSG_DIM + c] : 0.0f;
    }
    __syncthreads();

    const int R = wave * 16;
    const int arow = R + (lane & 15);
    const int kbase = (lane >> 4) * 8;
    const int ccol = lane & 15;
    const int crow0 = (lane >> 4) * 4;

    auto run_layer = [&](const short* __restrict__ pk, const float* __restrict__ bias,
                         int S, bool last) {
        f32x4 acc[8];
#pragma unroll
        for (int t = 0; t < 8; t++) acc[t] = (f32x4){0.f, 0.f, 0.f, 0.f};
        const int plane = 8 * S * 512;
        for (int s = 0; s < S; s++) {
            const float* ap = &lds[arow * 132 + 32 * s + kbase];
            f32x4 av0 = *(const f32x4*)ap;
            f32x4 av1 = *(const f32x4*)(ap + 4);
            float av[8] = {av0[0], av0[1], av0[2], av0[3], av1[0], av1[1], av1[2], av1[3]};
            bf16x8 ah, al;
            pack_split_rne(av, ah, al);
#pragma unroll
            for (int t = 0; t < 8; t++) {
                const short* bp = pk + ((size_t)(t * S + s) * 64 + lane) * 8;
                bf16x8 bh = *(const bf16x8*)bp;
                bf16x8 bl = *(const bf16x8*)(bp + plane);
                acc[t] = __builtin_amdgcn_mfma_f32_16x16x32_bf16(ah, bh, acc[t], 0, 0, 0);
                acc[t] = __builtin_amdgcn_mfma_f32_16x16x32_bf16(ah, bl, acc[t], 0, 0, 0);
                acc[t] = __builtin_amdgcn_mfma_f32_16x16x32_bf16(al, bh, acc[t], 0, 0, 0);
            }
        }
        __syncthreads();
#pragma unroll
        for (int t = 0; t < 8; t++) {
            float b = bias[16 * t + ccol];
#pragma unroll
            for (int r = 0; r < 4; r++) {
                float v = fmaxf(acc[t][r] + b, 0.0f);
                int row = R + crow0 + r;
                if (!last) {
                    lds[row * 132 + 16 * t + ccol] = v;
                } else {
                    int node = block0 + row;
                    if (node < n) out[(size_t)node * NHID + 16 * t + ccol] = v;
                }
            }
        }
        __syncthreads();
    };

    run_layer(pk1, b1, 3, false);
    run_layer(pk2, b2, 4, false);
    run_layer(pk3, b3, 4, true);
}

extern "C" void kernel_launch(void* const* d_in, const int* in_sizes, int n_in,
                              void* d_out, int out_size, void* d_ws, size_t ws_size,
                              hipStream_t stream)
{
    const float* X_msg    = (const float*)d_in[0];
    const float* feature  = (const float*)d_in[1];
    const float* te_w     = (const float*)d_in[2];
    const float* te_lam   = (const float*)d_in[3];
    const float* shared_w = (const float*)d_in[4];
    const float* shared_b = (const float*)d_in[5];
    const float* w_att_w  = (const float*)d_in[6];
    const float* w_att_b  = (const float*)d_in[7];
    const float* va       = (const float*)d_in[8];
    const float* w1       = (const float*)d_in[9];
    const float* b1       = (const float*)d_in[10];
    const float* w2       = (const float*)d_in[11];
    const float* b2       = (const float*)d_in[12];
    const float* w3       = (const float*)d_in[13];
    const float* b3       = (const float*)d_in[14];
    const int*   src      = (const int*)d_in[15];
    const int*   dst      = (const int*)d_in[16];
    const int*   dst_lane = (const int*)d_in[17];
    float* out = (float*)d_out;

    int N = in_sizes[0] / 2;   // X_msg (N,2)
    int E = in_sizes[15];      // src (E,)

    // workspace layout (4-byte units)
    float* att_perm = (float*)d_ws;              // E (fallback path only)
    int*   edge_ids = (int*)(att_perm + E);      // E (fallback path only)
    int*   perm     = edge_ids + E;              // E
    int*   offs     = perm + E;                  // N+1
    int*   woff     = offs + N + 1;              // N
    int*   counts   = woff + N;                  // N
    int*   bsums    = counts + N;                // 128
    float* h_att    = (float*)(bsums + 128);     // N*MSG_DIM
    short* pk1      = (short*)(h_att + (size_t)N * MSG_DIM);  // 24576 shorts
    short* pk2      = pk1 + 24576;                            // 32768 shorts
    short* pk3      = pk2 + 32768;                            // 32768 shorts
    short* pk_att   = pk3 + 32768;                            // 24576 shorts
    // 32B-align the record array
    size_t rec_off = (((size_t)((char*)(pk_att + 24576) - (char*)d_ws)) + 31) & ~(size_t)31;
    float* rec8    = (float*)((char*)d_ws + rec_off);         // E*8 floats

    size_t need = rec_off + (size_t)E * 8 * sizeof(float);
    int streams_ok = (ws_size >= need) ? 1 : 0;

    int ng = (N + 255) / 256;
    int eg = (E + 255) / 256;
    int nb = (N + SCAN_BLK - 1) / SCAN_BLK;

    hipMemsetAsync(counts, 0, (size_t)N * sizeof(int), stream);
    k_hist<<<eg, 256, 0, stream>>>(dst, counts, E);
    k_scan1<<<nb, 256, 0, stream>>>(counts, offs, bsums, N);
    k_scan2p<<<1, 128, 0, stream>>>(bsums, nb);
    k_scan3<<<ng, 256, 0, stream>>>(offs, woff, bsums, N, E);
    k_fill<<<eg, 256, 0, stream>>>(dst, woff, edge_ids, perm, 1 - streams_ok, E);

    k_prep<<<(57344 + 255) / 256, 256, 0, stream>>>(w1, w2, w3, w_att_w,
                                                    pk1, pk2, pk3, pk_att);

    k_att_mfma<<<(E + 63) / 64, 256, 0, stream>>>(
        X_msg, feature, te_w, te_lam, shared_w, shared_b,
        pk_att, w_att_b, va, src, dst, dst_lane, perm, att_perm,
        rec8, streams_ok, E);

    if (streams_ok) {
        k_gather_stream<<<(N + 15) / 16, 256, 0, stream>>>(
            te_w, te_lam, shared_w, shared_b, rec8, offs, h_att, N);
    } else {
        k_gather_wave<<<(N + 15) / 16, 256, 0, stream>>>(
            X_msg, feature, te_w, te_lam, shared_w, shared_b, src, dst_lane,
            att_perm, offs, edge_ids, h_att, N);
    }

    k_mlp_mfma<<<(N + 63) / 64, 256, 0, stream>>>(h_att, pk1, b1, pk2, b2, pk3, b3, out, N);
}